// Round 1
// 1548.933 us; speedup vs baseline: 1.5313x; 1.5313x over previous
//
#include <hip/hip_runtime.h>
#include <cstdint>
#include <cstddef>

// GRU last-hidden: B=1024, T=512, I=H=256.
// Phase 1 (k_proj): xi = x @ W_ih^T + b_ih  -> bf16 in workspace (chunked over T).
// Phase 2 (k_rec): persistent recurrence, 256 blocks x 4 batch rows, 8 waves.
//   Round-3 rework: a 512-thread block caps at 256 regs/wave (512-reg file/SIMD,
//   >=2 waves/SIMD), so the old 48-frag (192 reg) + 128 VGPR working set spilled
//   W to scratch (VGPR_Count=128 proved it). Now: 40 frags resident (160 regs),
//   6th gate-group read from LDS; gates on all 64 lanes via C-row replication
//   (A rows repeat mod 4 -> every q-group holds rows 0-3 in regs 0-3); xi loaded
//   straight to registers with depth-2 prefetch (no xish LDS, no vmcnt(0) at
//   barrier).

#define BB 1024
#define TT 512
#define II 256
#define HH 256
#define G3 768   // 3*H

using bfrag = __attribute__((ext_vector_type(8))) short;   // 8 bf16 = 4 VGPRs (guide §3)
using f32x4 = __attribute__((ext_vector_type(4))) float;   // MFMA C/D

static __device__ __forceinline__ unsigned short f2b(float f){
  unsigned u = __builtin_bit_cast(unsigned, f);
  u += 0x7FFFu + ((u >> 16) & 1u);          // RNE; inputs are finite
  return (unsigned short)(u >> 16);
}
static __device__ __forceinline__ float b2f(unsigned short s){
  unsigned u = ((unsigned)s) << 16;
  return __builtin_bit_cast(float, u);
}
static __device__ __forceinline__ float sigm(float x){
  float e = __builtin_amdgcn_exp2f(-1.4426950408889634f * x);
  return __builtin_amdgcn_rcpf(1.0f + e);
}
static __device__ __forceinline__ float tanh_(float x){
  float e = __builtin_amdgcn_exp2f(2.8853900817779268f * x);   // exp(2x)
  return (e - 1.0f) * __builtin_amdgcn_rcpf(e + 1.0f);
}
// select element q (runtime, 0..3) from an f32x4 with constant-index accesses only
static __device__ __forceinline__ float selq(f32x4 v, int q){
  float x01 = (q & 1) ? v[1] : v[0];
  float x23 = (q & 1) ? v[3] : v[2];
  return (q & 2) ? x23 : x01;
}

// ---------------------------------------------------------------------------
// k_init: convert W_ih / W_hh (fp32 [768][256]) to frag-major bf16:
//   out[((nt*8+ks)*64 + L)*8 + j] = W[nt*16 + (L&15)][ks*32 + (L>>4)*8 + j]
// so both GEMM kernels load B-frags as flat coalesced 16B/lane.
// Also zeroes persistent h and d_out (rows with seq_len==0 must stay 0).
// ---------------------------------------------------------------------------
__global__ void k_init(const float* __restrict__ Wih, const float* __restrict__ Whh,
                       unsigned short* __restrict__ Wihb, unsigned short* __restrict__ Whhb,
                       float* __restrict__ hws, float* __restrict__ out)
{
  int tid = blockIdx.x*256 + threadIdx.x;      // grid 1024*256 = 262144
  if (tid < 48*8*64*8){                        // 196608 weights per matrix
    int j  = tid & 7;
    int L  = (tid >> 3) & 63;
    int ks = (tid >> 9) & 7;
    int nt = tid >> 12;
    int src = (nt*16 + (L&15))*II + ks*32 + (L>>4)*8 + j;
    Wihb[tid] = f2b(Wih[src]);
    Whhb[tid] = f2b(Whh[src]);
  }
  if (tid < BB*HH){ hws[tid] = 0.0f; out[tid] = 0.0f; }
}

// ---------------------------------------------------------------------------
// k_proj: unchanged from the verified baseline (next-round target).
// 256 threads = 4 waves; each wave 4 m-tiles (64 rows), block 256 rows.
// ---------------------------------------------------------------------------
__global__ __launch_bounds__(256, 2) void k_proj(
    const float* __restrict__ x, const unsigned short* __restrict__ Wihb,
    const float* __restrict__ bih, unsigned short* __restrict__ xi,
    int t0, int Tc)
{
  __shared__ __align__(16) uint4 wsd[2048];    // 32KB: 4 n-tiles x 8 ks x 64 lanes
  const int tid = threadIdx.x, wv = tid>>6, L = tid&63;
  const int lr = L & 15, q = L >> 4;
  const int tpb = Tc >> 4;                     // m-tiles per batch row in chunk
  const int tile0 = blockIdx.x*16 + wv*4;

  bfrag a[4][8];
  int bs[4], tls[4];
#pragma unroll
  for (int m=0;m<4;++m){
    int tile = tile0 + m;
    int b = tile / tpb;
    int tl = (tile - b*tpb)*16;
    bs[m]=b; tls[m]=tl;
    const float* xr = x + ((size_t)b*TT + t0 + tl + lr)*II;
#pragma unroll
    for (int ks=0;ks<8;++ks){
      float4 v0 = *(const float4*)(xr + ks*32 + q*8);
      float4 v1 = *(const float4*)(xr + ks*32 + q*8 + 4);
      bfrag f;
      f[0]=(short)f2b(v0.x); f[1]=(short)f2b(v0.y); f[2]=(short)f2b(v0.z); f[3]=(short)f2b(v0.w);
      f[4]=(short)f2b(v1.x); f[5]=(short)f2b(v1.y); f[6]=(short)f2b(v1.z); f[7]=(short)f2b(v1.w);
      a[m][ks]=f;
    }
  }
  for (int nc=0; nc<12; ++nc){
    __syncthreads();                            // protect wsd reuse
    const uint4* wg = (const uint4*)Wihb + nc*2048;
#pragma unroll
    for (int it=0; it<8; ++it) wsd[it*256+tid] = wg[it*256+tid];
    __syncthreads();
    f32x4 acc[4][4];
#pragma unroll
    for (int nt=0;nt<4;++nt){
      float bv = bih[nc*64 + nt*16 + lr];       // bias folded into C
#pragma unroll
      for (int m=0;m<4;++m) acc[m][nt] = (f32x4){bv,bv,bv,bv};
    }
#pragma unroll
    for (int ks=0;ks<8;++ks){
#pragma unroll
      for (int nt=0;nt<4;++nt){
        bfrag bf = ((const bfrag*)wsd)[(nt*8+ks)*64 + L];
#pragma unroll
        for (int m=0;m<4;++m)
          acc[m][nt] = __builtin_amdgcn_mfma_f32_16x16x32_bf16(a[m][ks], bf, acc[m][nt], 0,0,0);
      }
    }
    // C/D layout: col = lane&15, row = (lane>>4)*4 + reg  (guide §3, m89-verified)
#pragma unroll
    for (int m=0;m<4;++m){
      unsigned short* o = xi + ((size_t)(tls[m] + 4*q)*BB + bs[m])*G3 + nc*64 + lr;
#pragma unroll
      for (int nt=0;nt<4;++nt)
#pragma unroll
        for (int r=0;r<4;++r)
          o[(size_t)r*BB*G3 + nt*16] = f2b(acc[m][nt][r]);
    }
  }
}

// ---------------------------------------------------------------------------
// k_rec: 256 blocks x 512 threads (8 waves), block owns 4 batch rows.
// Wave wv owns gh columns {32wv..32wv+31} in all 3 gates (6 frag groups);
// groups f=0..4 resident in regs (160), group f=5 (n-gate, p=1) in LDS (64KB).
// A-frag broadcast row = L&3 -> C rows repeat h-rows 0-3 across all q-groups,
// so lane (q,lr) runs gates for (row=q, cols c0,c1) with plain reg-selects.
// xi: per-lane global ushort loads, two named reg sets, 2-step prefetch depth.
// One __syncthreads per step.
// ---------------------------------------------------------------------------
__global__ __launch_bounds__(512, 2) void k_rec(
    const unsigned short* __restrict__ xi,    // [Tc][1024][768] bf16 (chunk-local)
    const unsigned short* __restrict__ Whhb,  // frag-major bf16
    const float* __restrict__ bhh,
    const int* __restrict__ seq,
    float* __restrict__ hws,                  // [1024][256] f32 persistent h
    float* __restrict__ out,                  // [1024][256] f32 hn
    int t0, int Tc)
{
  __shared__ __align__(16) unsigned short hsh[2][4*288];   // 4.5KB, stride 288
  __shared__ __align__(16) uint4 wlds[8*8*64];             // 64KB: f=5 frags, 8 waves
  const int tid = threadIdx.x;
  const int wv = tid >> 6;
  const int L  = tid & 63;
  const int lr = L & 15;
  const int q  = L >> 4;          // = h-row this lane's gates handle
  const int b0 = blockIdx.x * 4;
  const int c0 = 32*wv + lr, c1 = c0 + 16;

  // stage f=5 group (nt = 33 + 2*wv') into LDS: 4096 frags, 8 per thread
#pragma unroll
  for (int it = 0; it < 8; ++it){
    int idx = it*512 + tid;                       // (wv'*8 + ks)*64 + L
    int wvv = idx >> 9, kss = (idx >> 6) & 7, Ls = idx & 63;
    wlds[idx] = ((const uint4*)Whhb)[((33 + 2*wvv)*8 + kss)*64 + Ls];
  }

  // resident W_hh fragments (f=0..4) + per-column bias (folded into MFMA C)
  bfrag Wf[5][8];
  float bias[6];
#pragma unroll
  for (int g = 0; g < 3; ++g)
#pragma unroll
    for (int p = 0; p < 2; ++p){
      const int f  = g*2 + p;
      const int nt = g*16 + 2*wv + p;
      bias[f] = bhh[g*256 + 32*wv + 16*p + lr];
      if (f < 5){
#pragma unroll
        for (int ks = 0; ks < 8; ++ks)
          Wf[f][ks] = ((const bfrag*)Whhb)[(nt*8 + ks)*64 + L];
      }
    }

  // persistent h (fp32) for this lane's (row=q, cols c0,c1)
  float hp0 = hws[(b0+q)*HH + c0];
  float hp1 = hws[(b0+q)*HH + c1];
  int sl = seq[b0+q] - t0 - 1;                  // chunk-local step of last update
  float* op = out + (size_t)(b0+q)*HH + c0;
  hsh[0][q*288 + c0] = f2b(hp0);
  hsh[0][q*288 + c1] = f2b(hp1);

  // xi per-lane addressing: elem = t*BB*G3 + (b0+q)*G3 + gate*256 + col
  const int lo = (b0+q)*G3 + c0;
  const unsigned short* bE = xi;                 // even-t base (uniform)
  const unsigned short* bO = xi + (size_t)BB*G3; // odd-t base
  // depth-2 prefetch: two named register sets
  unsigned short xE0 = bE[lo],     xE1 = bE[lo+16],
                 xE2 = bE[lo+256], xE3 = bE[lo+272],
                 xE4 = bE[lo+512], xE5 = bE[lo+528];
  unsigned short xO0 = bO[lo],     xO1 = bO[lo+16],
                 xO2 = bO[lo+256], xO3 = bO[lo+272],
                 xO4 = bO[lo+512], xO5 = bO[lo+528];
  __syncthreads();                               // wlds + hsh[0] ready

  auto gru_step = [&](int curb, int nxtb,
                      unsigned short X0, unsigned short X1, unsigned short X2,
                      unsigned short X3, unsigned short X4, unsigned short X5,
                      int tcur){
    f32x4 acc[6];
#pragma unroll
    for (int f = 0; f < 6; ++f)
      acc[f] = (f32x4){bias[f], bias[f], bias[f], bias[f]};
#pragma unroll
    for (int ks = 0; ks < 8; ++ks){
      bfrag a  = *(const bfrag*)&hsh[curb][(L & 3)*288 + ks*32 + (L >> 4)*8];
      bfrag b5 = ((const bfrag*)wlds)[(wv*8 + ks)*64 + L];
      acc[0] = __builtin_amdgcn_mfma_f32_16x16x32_bf16(a, Wf[0][ks], acc[0], 0,0,0);
      acc[1] = __builtin_amdgcn_mfma_f32_16x16x32_bf16(a, Wf[1][ks], acc[1], 0,0,0);
      acc[2] = __builtin_amdgcn_mfma_f32_16x16x32_bf16(a, Wf[2][ks], acc[2], 0,0,0);
      acc[3] = __builtin_amdgcn_mfma_f32_16x16x32_bf16(a, Wf[3][ks], acc[3], 0,0,0);
      acc[4] = __builtin_amdgcn_mfma_f32_16x16x32_bf16(a, Wf[4][ks], acc[4], 0,0,0);
      acc[5] = __builtin_amdgcn_mfma_f32_16x16x32_bf16(a, b5,        acc[5], 0,0,0);
    }
    // every q-group holds h-rows 0-3 in regs 0-3 (A rows repeat mod 4):
    // this lane consumes reg q of each acc for its (row=q, cols c0/c1).
    float gr0 = selq(acc[0], q), gr1 = selq(acc[1], q);
    float gz0 = selq(acc[2], q), gz1 = selq(acc[3], q);
    float gn0 = selq(acc[4], q), gn1 = selq(acc[5], q);
    float r0 = sigm(b2f(X0) + gr0), r1 = sigm(b2f(X1) + gr1);
    float z0 = sigm(b2f(X2) + gz0), z1 = sigm(b2f(X3) + gz1);
    float n0 = tanh_(b2f(X4) + r0*gn0), n1 = tanh_(b2f(X5) + r1*gn1);
    float h0 = n0 + z0*(hp0 - n0);              // (1-z)n + z*h
    float h1 = n1 + z1*(hp1 - n1);
    hp0 = h0; hp1 = h1;
    hsh[nxtb][q*288 + c0] = f2b(h0);
    hsh[nxtb][q*288 + c1] = f2b(h1);
    if (tcur == sl){ op[0] = h0; op[16] = h1; }
  };

  const size_t tadv = 2*(size_t)BB*G3;
  for (int tl = 0; tl < Tc; tl += 2){
    gru_step(0, 1, xE0, xE1, xE2, xE3, xE4, xE5, tl);
    if (tl + 2 < Tc) bE += tadv;                 // clamp: final reload is dead
    xE0 = bE[lo];     xE1 = bE[lo+16];
    xE2 = bE[lo+256]; xE3 = bE[lo+272];
    xE4 = bE[lo+512]; xE5 = bE[lo+528];
    __syncthreads();
    gru_step(1, 0, xO0, xO1, xO2, xO3, xO4, xO5, tl + 1);
    if (tl + 3 < Tc) bO += tadv;
    xO0 = bO[lo];     xO1 = bO[lo+16];
    xO2 = bO[lo+256]; xO3 = bO[lo+272];
    xO4 = bO[lo+512]; xO5 = bO[lo+528];
    __syncthreads();
  }
  hws[(b0+q)*HH + c0] = hp0;
  hws[(b0+q)*HH + c1] = hp1;
}

// ---------------------------------------------------------------------------
// ws layout: [0, 384K) W_hh frag-bf16 | [384K, 768K) W_ih frag-bf16
//            [1M, 2M) persistent h fp32 | [3M, ...) xi chunk bf16
// Tc auto-halved until the chunk fits ws (needs >= ~27MB at Tc=16).
// ---------------------------------------------------------------------------
extern "C" void kernel_launch(void* const* d_in, const int* in_sizes, int n_in,
                              void* d_out, int out_size, void* d_ws, size_t ws_size,
                              hipStream_t stream)
{
  (void)in_sizes; (void)n_in; (void)out_size;
  const float* x   = (const float*)d_in[0];
  const int*   seq = (const int*)  d_in[1];
  const float* Wih = (const float*)d_in[2];
  const float* Whh = (const float*)d_in[3];
  const float* bih = (const float*)d_in[4];
  const float* bhh = (const float*)d_in[5];
  float* out = (float*)d_out;
  char* ws = (char*)d_ws;
  unsigned short* Whhb = (unsigned short*)(ws);
  unsigned short* Wihb = (unsigned short*)(ws + 393216);
  float* hws = (float*)(ws + (1u<<20));
  unsigned short* xiw = (unsigned short*)(ws + 3u*(1u<<20));
  size_t avail = (ws_size > (size_t)(3u<<20)) ? ws_size - (size_t)(3u<<20) : 0;
  int Tc = TT;
  while (Tc > 16 && (size_t)Tc*BB*G3*2 > avail) Tc >>= 1;

  k_init<<<dim3(1024), dim3(256), 0, stream>>>(Wih, Whh, Wihb, Whhb, hws, out);
  for (int t0 = 0; t0 < TT; t0 += Tc){
    k_proj<<<dim3((BB/256)*Tc), dim3(256), 0, stream>>>(x, Wihb, bih, xiw, t0, Tc);
    k_rec <<<dim3(256), dim3(512), 0, stream>>>(xiw, Whhb, bhh, seq, hws, out, t0, Tc);
  }
}

// Round 2
// 1534.407 us; speedup vs baseline: 1.5458x; 1.0095x over previous
//
#include <hip/hip_runtime.h>
#include <cstdint>
#include <cstddef>

// GRU last-hidden: B=1024, T=512, I=H=256.
// Phase 1 (k_proj): xi = x @ W_ih^T + (b_ih + b_hh[r,z])  -> bf16 in workspace.
// Phase 2 (k_rec): persistent recurrence, 256 blocks x 4 batch rows, 8 waves.
//   Round-2 lesson: VGPR_Count=124 < 160 proved the compiler REMATERIALIZED the
//   "resident" W_hh frags from global every step (327 KB/CU/step through L2 =
//   the whole 6240 cy/step). Fix: all 48 frags (192 VGPR) loaded once and
//   pinned with asm("" : "+v") so they cannot be remat'd; wlds LDS buffer gone.
//   Barriers are raw s_barrier + lgkmcnt(0) (no vmcnt(0) drain), so the xi
//   register prefetch genuinely stays in flight across steps (~2-step budget).
//   b_hh r/z parts folded into k_proj bias; b_hh n-part stays in acc init
//   (it is multiplied by r inside the n gate and must NOT be folded).

#define BB 1024
#define TT 512
#define II 256
#define HH 256
#define G3 768   // 3*H

using bfrag = __attribute__((ext_vector_type(8))) short;   // 8 bf16 = 4 VGPRs (guide §3)
using f32x4 = __attribute__((ext_vector_type(4))) float;   // MFMA C/D

static __device__ __forceinline__ unsigned short f2b(float f){
  unsigned u = __builtin_bit_cast(unsigned, f);
  u += 0x7FFFu + ((u >> 16) & 1u);          // RNE; inputs are finite
  return (unsigned short)(u >> 16);
}
static __device__ __forceinline__ float b2f(unsigned short s){
  unsigned u = ((unsigned)s) << 16;
  return __builtin_bit_cast(float, u);
}
static __device__ __forceinline__ float sigm(float x){
  float e = __builtin_amdgcn_exp2f(-1.4426950408889634f * x);
  return __builtin_amdgcn_rcpf(1.0f + e);
}
static __device__ __forceinline__ float tanh_(float x){
  float e = __builtin_amdgcn_exp2f(2.8853900817779268f * x);   // exp(2x)
  return (e - 1.0f) * __builtin_amdgcn_rcpf(e + 1.0f);
}
// select element q (runtime, 0..3) from an f32x4 with constant-index accesses only
static __device__ __forceinline__ float selq(f32x4 v, int q){
  float x01 = (q & 1) ? v[1] : v[0];
  float x23 = (q & 1) ? v[3] : v[2];
  return (q & 2) ? x23 : x01;
}
static __device__ __forceinline__ void barrier_lgkm(){
  asm volatile("s_waitcnt lgkmcnt(0)" ::: "memory");
  __builtin_amdgcn_s_barrier();
}

// ---------------------------------------------------------------------------
// k_init: convert W_ih / W_hh (fp32 [768][256]) to frag-major bf16:
//   out[((nt*8+ks)*64 + L)*8 + j] = W[nt*16 + (L&15)][ks*32 + (L>>4)*8 + j]
// so both GEMM kernels load B-frags as flat coalesced 16B/lane.
// Also: bsum[768] = b_ih + (gate<n ? b_hh : 0)  (r/z bias folded into xi).
// Also zeroes persistent h and d_out (rows with seq_len==0 must stay 0).
// ---------------------------------------------------------------------------
__global__ void k_init(const float* __restrict__ Wih, const float* __restrict__ Whh,
                       const float* __restrict__ bih, const float* __restrict__ bhh,
                       unsigned short* __restrict__ Wihb, unsigned short* __restrict__ Whhb,
                       float* __restrict__ bsum,
                       float* __restrict__ hws, float* __restrict__ out)
{
  int tid = blockIdx.x*256 + threadIdx.x;      // grid 1024*256 = 262144
  if (tid < 48*8*64*8){                        // 196608 weights per matrix
    int j  = tid & 7;
    int L  = (tid >> 3) & 63;
    int ks = (tid >> 9) & 7;
    int nt = tid >> 12;
    int src = (nt*16 + (L&15))*II + ks*32 + (L>>4)*8 + j;
    Wihb[tid] = f2b(Wih[src]);
    Whhb[tid] = f2b(Whh[src]);
  }
  if (tid < G3) bsum[tid] = bih[tid] + (tid < 512 ? bhh[tid] : 0.0f);
  if (tid < BB*HH){ hws[tid] = 0.0f; out[tid] = 0.0f; }
}

// ---------------------------------------------------------------------------
// k_proj: unchanged structurally (bias source is now bsum).
// 256 threads = 4 waves; each wave 4 m-tiles (64 rows), block 256 rows.
// ---------------------------------------------------------------------------
__global__ __launch_bounds__(256, 2) void k_proj(
    const float* __restrict__ x, const unsigned short* __restrict__ Wihb,
    const float* __restrict__ bsum, unsigned short* __restrict__ xi,
    int t0, int Tc)
{
  __shared__ __align__(16) uint4 wsd[2048];    // 32KB: 4 n-tiles x 8 ks x 64 lanes
  const int tid = threadIdx.x, wv = tid>>6, L = tid&63;
  const int lr = L & 15, q = L >> 4;
  const int tpb = Tc >> 4;                     // m-tiles per batch row in chunk
  const int tile0 = blockIdx.x*16 + wv*4;

  bfrag a[4][8];
  int bs[4], tls[4];
#pragma unroll
  for (int m=0;m<4;++m){
    int tile = tile0 + m;
    int b = tile / tpb;
    int tl = (tile - b*tpb)*16;
    bs[m]=b; tls[m]=tl;
    const float* xr = x + ((size_t)b*TT + t0 + tl + lr)*II;
#pragma unroll
    for (int ks=0;ks<8;++ks){
      float4 v0 = *(const float4*)(xr + ks*32 + q*8);
      float4 v1 = *(const float4*)(xr + ks*32 + q*8 + 4);
      bfrag f;
      f[0]=(short)f2b(v0.x); f[1]=(short)f2b(v0.y); f[2]=(short)f2b(v0.z); f[3]=(short)f2b(v0.w);
      f[4]=(short)f2b(v1.x); f[5]=(short)f2b(v1.y); f[6]=(short)f2b(v1.z); f[7]=(short)f2b(v1.w);
      a[m][ks]=f;
    }
  }
  for (int nc=0; nc<12; ++nc){
    __syncthreads();                            // protect wsd reuse
    const uint4* wg = (const uint4*)Wihb + nc*2048;
#pragma unroll
    for (int it=0; it<8; ++it) wsd[it*256+tid] = wg[it*256+tid];
    __syncthreads();
    f32x4 acc[4][4];
#pragma unroll
    for (int nt=0;nt<4;++nt){
      float bv = bsum[nc*64 + nt*16 + lr];      // bias folded into C
#pragma unroll
      for (int m=0;m<4;++m) acc[m][nt] = (f32x4){bv,bv,bv,bv};
    }
#pragma unroll
    for (int ks=0;ks<8;++ks){
#pragma unroll
      for (int nt=0;nt<4;++nt){
        bfrag bf = ((const bfrag*)wsd)[(nt*8+ks)*64 + L];
#pragma unroll
        for (int m=0;m<4;++m)
          acc[m][nt] = __builtin_amdgcn_mfma_f32_16x16x32_bf16(a[m][ks], bf, acc[m][nt], 0,0,0);
      }
    }
    // C/D layout: col = lane&15, row = (lane>>4)*4 + reg  (guide §3, m89-verified)
#pragma unroll
    for (int m=0;m<4;++m){
      unsigned short* o = xi + ((size_t)(tls[m] + 4*q)*BB + bs[m])*G3 + nc*64 + lr;
#pragma unroll
      for (int nt=0;nt<4;++nt)
#pragma unroll
        for (int r=0;r<4;++r)
          o[(size_t)r*BB*G3 + nt*16] = f2b(acc[m][nt][r]);
    }
  }
}

// ---------------------------------------------------------------------------
// k_rec: 256 blocks x 512 threads (8 waves), block owns 4 batch rows.
// Wave wv owns gh columns {32wv..32wv+31} in all 3 gates = 6 frag groups,
// ALL resident: Wf[6][8] = 192 VGPRs, asm-pinned against remat.
// A-frag broadcast row = L&3 -> C rows repeat h-rows 0-3 across all q-groups,
// so lane (q,lr) runs gates for (row=q, cols c0,c1) with plain reg-selects.
// xi: per-lane global ushort loads, two named reg sets; raw barriers keep the
// loads in flight across steps (~2-step latency budget).
// ---------------------------------------------------------------------------
__global__ __launch_bounds__(512, 2) void k_rec(
    const unsigned short* __restrict__ xi,    // [Tc][1024][768] bf16 (chunk-local)
    const unsigned short* __restrict__ Whhb,  // frag-major bf16
    const float* __restrict__ bhh,
    const int* __restrict__ seq,
    float* __restrict__ hws,                  // [1024][256] f32 persistent h
    float* __restrict__ out,                  // [1024][256] f32 hn
    int t0, int Tc)
{
  __shared__ __align__(16) unsigned short hsh[2][4*288];   // 4.5KB, stride 288
  const int tid = threadIdx.x;
  const int wv = tid >> 6;
  const int L  = tid & 63;
  const int lr = L & 15;
  const int q  = L >> 4;          // = h-row this lane's gates handle
  const int b0 = blockIdx.x * 4;
  const int c0 = 32*wv + lr, c1 = c0 + 16;

  // all 48 resident W_hh fragments (192 VGPRs), pinned
  bfrag Wf[6][8];
#pragma unroll
  for (int g = 0; g < 3; ++g)
#pragma unroll
    for (int p = 0; p < 2; ++p){
      const int f  = g*2 + p;
      const int nt = g*16 + 2*wv + p;
#pragma unroll
      for (int ks = 0; ks < 8; ++ks)
        Wf[f][ks] = ((const bfrag*)Whhb)[(nt*8 + ks)*64 + L];
    }
#pragma unroll
  for (int f = 0; f < 6; ++f)
#pragma unroll
    for (int ks = 0; ks < 8; ++ks)
      asm volatile("" : "+v"(Wf[f][ks]));     // asm-defined: cannot be remat'd

  // n-gate bias (multiplied by r inside the gate -> not foldable into xi)
  const float bn0 = bhh[512 + 32*wv + lr];
  const float bn1 = bhh[512 + 32*wv + 16 + lr];

  // persistent h (fp32) for this lane's (row=q, cols c0,c1)
  float hp0 = hws[(b0+q)*HH + c0];
  float hp1 = hws[(b0+q)*HH + c1];
  const int sl = seq[b0+q] - t0 - 1;            // chunk-local step of last update
  hsh[0][q*288 + c0] = f2b(hp0);
  hsh[0][q*288 + c1] = f2b(hp1);

  // xi per-lane addressing: elem = t*BB*G3 + (b0+q)*G3 + gate*256 + col
  const int lo = (b0+q)*G3 + c0;
  const unsigned short* bE = xi;                 // even-t base
  const unsigned short* bO = xi + (size_t)BB*G3; // odd-t base
  unsigned short xE0 = bE[lo],     xE1 = bE[lo+16],
                 xE2 = bE[lo+256], xE3 = bE[lo+272],
                 xE4 = bE[lo+512], xE5 = bE[lo+528];
  unsigned short xO0 = bO[lo],     xO1 = bO[lo+16],
                 xO2 = bO[lo+256], xO3 = bO[lo+272],
                 xO4 = bO[lo+512], xO5 = bO[lo+528];
  barrier_lgkm();                                // hsh[0] ready

  auto gru_step = [&](int curb, int nxtb,
                      unsigned short X0, unsigned short X1, unsigned short X2,
                      unsigned short X3, unsigned short X4, unsigned short X5,
                      int tcur){
    f32x4 acc[6];
    acc[0] = (f32x4){0.f,0.f,0.f,0.f};
    acc[1] = (f32x4){0.f,0.f,0.f,0.f};
    acc[2] = (f32x4){0.f,0.f,0.f,0.f};
    acc[3] = (f32x4){0.f,0.f,0.f,0.f};
    acc[4] = (f32x4){bn0,bn0,bn0,bn0};
    acc[5] = (f32x4){bn1,bn1,bn1,bn1};
#pragma unroll
    for (int ks = 0; ks < 8; ++ks){
      bfrag a = *(const bfrag*)&hsh[curb][(L & 3)*288 + ks*32 + (L >> 4)*8];
      acc[0] = __builtin_amdgcn_mfma_f32_16x16x32_bf16(a, Wf[0][ks], acc[0], 0,0,0);
      acc[1] = __builtin_amdgcn_mfma_f32_16x16x32_bf16(a, Wf[1][ks], acc[1], 0,0,0);
      acc[2] = __builtin_amdgcn_mfma_f32_16x16x32_bf16(a, Wf[2][ks], acc[2], 0,0,0);
      acc[3] = __builtin_amdgcn_mfma_f32_16x16x32_bf16(a, Wf[3][ks], acc[3], 0,0,0);
      acc[4] = __builtin_amdgcn_mfma_f32_16x16x32_bf16(a, Wf[4][ks], acc[4], 0,0,0);
      acc[5] = __builtin_amdgcn_mfma_f32_16x16x32_bf16(a, Wf[5][ks], acc[5], 0,0,0);
    }
    // every q-group holds h-rows 0-3 in regs 0-3 (A rows repeat mod 4):
    // this lane consumes reg q of each acc for its (row=q, cols c0/c1).
    float gr0 = selq(acc[0], q), gr1 = selq(acc[1], q);
    float gz0 = selq(acc[2], q), gz1 = selq(acc[3], q);
    float gn0 = selq(acc[4], q), gn1 = selq(acc[5], q);
    float r0 = sigm(b2f(X0) + gr0), r1 = sigm(b2f(X1) + gr1);
    float z0 = sigm(b2f(X2) + gz0), z1 = sigm(b2f(X3) + gz1);
    float n0 = tanh_(b2f(X4) + r0*gn0), n1 = tanh_(b2f(X5) + r1*gn1);
    float h0 = n0 + z0*(hp0 - n0);              // (1-z)n + z*h
    float h1 = n1 + z1*(hp1 - n1);
    hp0 = h0; hp1 = h1;
    hsh[nxtb][q*288 + c0] = f2b(h0);
    hsh[nxtb][q*288 + c1] = f2b(h1);
    if (tcur == sl){                             // last step with t+1<=seq_len
      float* o = out + (size_t)(b0+q)*HH + c0;
      o[0] = h0; o[16] = h1;
    }
  };

  const size_t tadv = 2*(size_t)BB*G3;
  for (int tl = 0; tl < Tc; tl += 2){
    // issue E-reload (for t+2) first: stays in flight across both raw barriers
    if (tl + 2 < Tc) bE += tadv;                 // clamp: final reload is dead
    unsigned short nE0 = bE[lo],     nE1 = bE[lo+16],
                   nE2 = bE[lo+256], nE3 = bE[lo+272],
                   nE4 = bE[lo+512], nE5 = bE[lo+528];
    gru_step(0, 1, xE0, xE1, xE2, xE3, xE4, xE5, tl);
    xE0=nE0; xE1=nE1; xE2=nE2; xE3=nE3; xE4=nE4; xE5=nE5;
    barrier_lgkm();
    if (tl + 3 < Tc) bO += tadv;
    unsigned short nO0 = bO[lo],     nO1 = bO[lo+16],
                   nO2 = bO[lo+256], nO3 = bO[lo+272],
                   nO4 = bO[lo+512], nO5 = bO[lo+528];
    gru_step(1, 0, xO0, xO1, xO2, xO3, xO4, xO5, tl + 1);
    xO0=nO0; xO1=nO1; xO2=nO2; xO3=nO3; xO4=nO4; xO5=nO5;
    barrier_lgkm();
  }
  hws[(b0+q)*HH + c0] = hp0;
  hws[(b0+q)*HH + c1] = hp1;
}

// ---------------------------------------------------------------------------
// ws layout: [0, 384K) W_hh frag-bf16 | [384K, 768K) W_ih frag-bf16
//            [768K, 768K+3K) bsum fp32 | [1M, 2M) persistent h fp32
//            [3M, ...) xi chunk bf16.  Tc auto-halved until chunk fits ws.
// ---------------------------------------------------------------------------
extern "C" void kernel_launch(void* const* d_in, const int* in_sizes, int n_in,
                              void* d_out, int out_size, void* d_ws, size_t ws_size,
                              hipStream_t stream)
{
  (void)in_sizes; (void)n_in; (void)out_size;
  const float* x   = (const float*)d_in[0];
  const int*   seq = (const int*)  d_in[1];
  const float* Wih = (const float*)d_in[2];
  const float* Whh = (const float*)d_in[3];
  const float* bih = (const float*)d_in[4];
  const float* bhh = (const float*)d_in[5];
  float* out = (float*)d_out;
  char* ws = (char*)d_ws;
  unsigned short* Whhb = (unsigned short*)(ws);
  unsigned short* Wihb = (unsigned short*)(ws + 393216);
  float* bsum = (float*)(ws + 786432);
  float* hws = (float*)(ws + (1u<<20));
  unsigned short* xiw = (unsigned short*)(ws + 3u*(1u<<20));
  size_t avail = (ws_size > (size_t)(3u<<20)) ? ws_size - (size_t)(3u<<20) : 0;
  int Tc = TT;
  while (Tc > 16 && (size_t)Tc*BB*G3*2 > avail) Tc >>= 1;

  k_init<<<dim3(1024), dim3(256), 0, stream>>>(Wih, Whh, bih, bhh, Wihb, Whhb, bsum, hws, out);
  for (int t0 = 0; t0 < TT; t0 += Tc){
    k_proj<<<dim3((BB/256)*Tc), dim3(256), 0, stream>>>(x, Wihb, bsum, xiw, t0, Tc);
    k_rec <<<dim3(256), dim3(512), 0, stream>>>(xiw, Whhb, bhh, seq, hws, out, t0, Tc);
  }
}

// Round 3
// 1518.175 us; speedup vs baseline: 1.5624x; 1.0107x over previous
//
#include <hip/hip_runtime.h>
#include <cstdint>
#include <cstddef>

// GRU last-hidden: B=1024, T=512, I=H=256.
// Phase 1 (k_proj): xi = x @ W_ih^T + (b_ih + b_hh[r,z])  -> bf16 in workspace.
// Phase 2 (k_rec): persistent recurrence, 256 blocks x 4 batch rows, 8 waves.
//   Round-3 lesson: VGPR_Count=128 in BOTH prior rounds -- __launch_bounds__(512,2)
//   made the allocator budget 128 regs/wave (4 waves/EU), so the 192-reg Wf set
//   was scratch-spilled and reloaded every step (~128-256 KB/CU/step via L1/L2 =
//   the ~5300 missing cy/step; invisible in FETCH because L2-resident).
//   Fix: amdgpu_waves_per_eu(2,2) pins the budget to exactly 256 regs/wave --
//   the allocator cannot spill to chase higher occupancy. Peak live ~253.
//   xi reloaded in place (no nE/nO temps) to trim the transient peak.

#define BB 1024
#define TT 512
#define II 256
#define HH 256
#define G3 768   // 3*H

using bfrag = __attribute__((ext_vector_type(8))) short;   // 8 bf16 = 4 VGPRs (guide §3)
using f32x4 = __attribute__((ext_vector_type(4))) float;   // MFMA C/D

static __device__ __forceinline__ unsigned short f2b(float f){
  unsigned u = __builtin_bit_cast(unsigned, f);
  u += 0x7FFFu + ((u >> 16) & 1u);          // RNE; inputs are finite
  return (unsigned short)(u >> 16);
}
static __device__ __forceinline__ float b2f(unsigned short s){
  unsigned u = ((unsigned)s) << 16;
  return __builtin_bit_cast(float, u);
}
static __device__ __forceinline__ float sigm(float x){
  float e = __builtin_amdgcn_exp2f(-1.4426950408889634f * x);
  return __builtin_amdgcn_rcpf(1.0f + e);
}
static __device__ __forceinline__ float tanh_(float x){
  float e = __builtin_amdgcn_exp2f(2.8853900817779268f * x);   // exp(2x)
  return (e - 1.0f) * __builtin_amdgcn_rcpf(e + 1.0f);
}
// select element q (runtime, 0..3) from an f32x4 with constant-index accesses only
static __device__ __forceinline__ float selq(f32x4 v, int q){
  float x01 = (q & 1) ? v[1] : v[0];
  float x23 = (q & 1) ? v[3] : v[2];
  return (q & 2) ? x23 : x01;
}
static __device__ __forceinline__ void barrier_lgkm(){
  asm volatile("s_waitcnt lgkmcnt(0)" ::: "memory");
  __builtin_amdgcn_s_barrier();
}

// ---------------------------------------------------------------------------
// k_init: convert W_ih / W_hh (fp32 [768][256]) to frag-major bf16:
//   out[((nt*8+ks)*64 + L)*8 + j] = W[nt*16 + (L&15)][ks*32 + (L>>4)*8 + j]
// so both GEMM kernels load B-frags as flat coalesced 16B/lane.
// Also: bsum[768] = b_ih + (gate<n ? b_hh : 0)  (r/z bias folded into xi).
// Also zeroes persistent h and d_out (rows with seq_len==0 must stay 0).
// ---------------------------------------------------------------------------
__global__ void k_init(const float* __restrict__ Wih, const float* __restrict__ Whh,
                       const float* __restrict__ bih, const float* __restrict__ bhh,
                       unsigned short* __restrict__ Wihb, unsigned short* __restrict__ Whhb,
                       float* __restrict__ bsum,
                       float* __restrict__ hws, float* __restrict__ out)
{
  int tid = blockIdx.x*256 + threadIdx.x;      // grid 1024*256 = 262144
  if (tid < 48*8*64*8){                        // 196608 weights per matrix
    int j  = tid & 7;
    int L  = (tid >> 3) & 63;
    int ks = (tid >> 9) & 7;
    int nt = tid >> 12;
    int src = (nt*16 + (L&15))*II + ks*32 + (L>>4)*8 + j;
    Wihb[tid] = f2b(Wih[src]);
    Whhb[tid] = f2b(Whh[src]);
  }
  if (tid < G3) bsum[tid] = bih[tid] + (tid < 512 ? bhh[tid] : 0.0f);
  if (tid < BB*HH){ hws[tid] = 0.0f; out[tid] = 0.0f; }
}

// ---------------------------------------------------------------------------
// k_proj: unchanged (measures ~92 us/dispatch ~= 1.1 PF effective -- leave it).
// 256 threads = 4 waves; each wave 4 m-tiles (64 rows), block 256 rows.
// ---------------------------------------------------------------------------
__global__ __launch_bounds__(256, 2) void k_proj(
    const float* __restrict__ x, const unsigned short* __restrict__ Wihb,
    const float* __restrict__ bsum, unsigned short* __restrict__ xi,
    int t0, int Tc)
{
  __shared__ __align__(16) uint4 wsd[2048];    // 32KB: 4 n-tiles x 8 ks x 64 lanes
  const int tid = threadIdx.x, wv = tid>>6, L = tid&63;
  const int lr = L & 15, q = L >> 4;
  const int tpb = Tc >> 4;                     // m-tiles per batch row in chunk
  const int tile0 = blockIdx.x*16 + wv*4;

  bfrag a[4][8];
  int bs[4], tls[4];
#pragma unroll
  for (int m=0;m<4;++m){
    int tile = tile0 + m;
    int b = tile / tpb;
    int tl = (tile - b*tpb)*16;
    bs[m]=b; tls[m]=tl;
    const float* xr = x + ((size_t)b*TT + t0 + tl + lr)*II;
#pragma unroll
    for (int ks=0;ks<8;++ks){
      float4 v0 = *(const float4*)(xr + ks*32 + q*8);
      float4 v1 = *(const float4*)(xr + ks*32 + q*8 + 4);
      bfrag f;
      f[0]=(short)f2b(v0.x); f[1]=(short)f2b(v0.y); f[2]=(short)f2b(v0.z); f[3]=(short)f2b(v0.w);
      f[4]=(short)f2b(v1.x); f[5]=(short)f2b(v1.y); f[6]=(short)f2b(v1.z); f[7]=(short)f2b(v1.w);
      a[m][ks]=f;
    }
  }
  for (int nc=0; nc<12; ++nc){
    __syncthreads();                            // protect wsd reuse
    const uint4* wg = (const uint4*)Wihb + nc*2048;
#pragma unroll
    for (int it=0; it<8; ++it) wsd[it*256+tid] = wg[it*256+tid];
    __syncthreads();
    f32x4 acc[4][4];
#pragma unroll
    for (int nt=0;nt<4;++nt){
      float bv = bsum[nc*64 + nt*16 + lr];      // bias folded into C
#pragma unroll
      for (int m=0;m<4;++m) acc[m][nt] = (f32x4){bv,bv,bv,bv};
    }
#pragma unroll
    for (int ks=0;ks<8;++ks){
#pragma unroll
      for (int nt=0;nt<4;++nt){
        bfrag bf = ((const bfrag*)wsd)[(nt*8+ks)*64 + L];
#pragma unroll
        for (int m=0;m<4;++m)
          acc[m][nt] = __builtin_amdgcn_mfma_f32_16x16x32_bf16(a[m][ks], bf, acc[m][nt], 0,0,0);
      }
    }
    // C/D layout: col = lane&15, row = (lane>>4)*4 + reg  (guide §3, m89-verified)
#pragma unroll
    for (int m=0;m<4;++m){
      unsigned short* o = xi + ((size_t)(tls[m] + 4*q)*BB + bs[m])*G3 + nc*64 + lr;
#pragma unroll
      for (int nt=0;nt<4;++nt)
#pragma unroll
        for (int r=0;r<4;++r)
          o[(size_t)r*BB*G3 + nt*16] = f2b(acc[m][nt][r]);
    }
  }
}

// ---------------------------------------------------------------------------
// k_rec: 256 blocks x 512 threads (8 waves), block owns 4 batch rows.
// Wave wv owns gh columns {32wv..32wv+31} in all 3 gates = 6 frag groups,
// ALL resident: Wf[6][8] = 192 VGPRs. waves_per_eu(2,2) pins the register
// budget to 256/wave so the allocator cannot spill Wf for occupancy.
// A-frag broadcast row = L&3 -> C rows repeat h-rows 0-3 across all q-groups,
// so lane (q,lr) runs gates for (row=q, cols c0,c1) with plain reg-selects.
// xi: per-lane global ushort loads reloaded in place after consumption
// (~2 steps of latency budget); raw lgkm barriers keep them in flight.
// ---------------------------------------------------------------------------
__global__
__attribute__((amdgpu_flat_work_group_size(512, 512), amdgpu_waves_per_eu(2, 2)))
void k_rec(
    const unsigned short* __restrict__ xi,    // [Tc][1024][768] bf16 (chunk-local)
    const unsigned short* __restrict__ Whhb,  // frag-major bf16
    const float* __restrict__ bhh,
    const int* __restrict__ seq,
    float* __restrict__ hws,                  // [1024][256] f32 persistent h
    float* __restrict__ out,                  // [1024][256] f32 hn
    int t0, int Tc)
{
  __shared__ __align__(16) unsigned short hsh[2][4*288];   // 4.5KB, stride 288
  const int tid = threadIdx.x;
  const int wv = tid >> 6;
  const int L  = tid & 63;
  const int lr = L & 15;
  const int q  = L >> 4;          // = h-row this lane's gates handle
  const int b0 = blockIdx.x * 4;
  const int c0 = 32*wv + lr, c1 = c0 + 16;

  // all 48 resident W_hh fragments (192 VGPRs), pinned against remat
  bfrag Wf[6][8];
#pragma unroll
  for (int g = 0; g < 3; ++g)
#pragma unroll
    for (int p = 0; p < 2; ++p){
      const int f  = g*2 + p;
      const int nt = g*16 + 2*wv + p;
#pragma unroll
      for (int ks = 0; ks < 8; ++ks)
        Wf[f][ks] = ((const bfrag*)Whhb)[(nt*8 + ks)*64 + L];
    }
#pragma unroll
  for (int f = 0; f < 6; ++f)
#pragma unroll
    for (int ks = 0; ks < 8; ++ks)
      asm volatile("" : "+v"(Wf[f][ks]));     // asm-defined: cannot be remat'd

  // n-gate bias (multiplied by r inside the gate -> not foldable into xi)
  const float bn0 = bhh[512 + 32*wv + lr];
  const float bn1 = bhh[512 + 32*wv + 16 + lr];

  // persistent h (fp32) for this lane's (row=q, cols c0,c1)
  float hp0 = hws[(b0+q)*HH + c0];
  float hp1 = hws[(b0+q)*HH + c1];
  const int sl = seq[b0+q] - t0 - 1;            // chunk-local step of last update
  hsh[0][q*288 + c0] = f2b(hp0);
  hsh[0][q*288 + c1] = f2b(hp1);

  // xi per-lane addressing: elem = t*BB*G3 + (b0+q)*G3 + gate*256 + col
  const int lo = (b0+q)*G3 + c0;
  const unsigned short* bE = xi;                 // even-t base
  const unsigned short* bO = xi + (size_t)BB*G3; // odd-t base
  unsigned short xE0 = bE[lo],     xE1 = bE[lo+16],
                 xE2 = bE[lo+256], xE3 = bE[lo+272],
                 xE4 = bE[lo+512], xE5 = bE[lo+528];
  unsigned short xO0 = bO[lo],     xO1 = bO[lo+16],
                 xO2 = bO[lo+256], xO3 = bO[lo+272],
                 xO4 = bO[lo+512], xO5 = bO[lo+528];
  barrier_lgkm();                                // hsh[0] ready

  auto gru_step = [&](int curb, int nxtb,
                      unsigned short X0, unsigned short X1, unsigned short X2,
                      unsigned short X3, unsigned short X4, unsigned short X5,
                      int tcur){
    f32x4 acc[6];
    acc[0] = (f32x4){0.f,0.f,0.f,0.f};
    acc[1] = (f32x4){0.f,0.f,0.f,0.f};
    acc[2] = (f32x4){0.f,0.f,0.f,0.f};
    acc[3] = (f32x4){0.f,0.f,0.f,0.f};
    acc[4] = (f32x4){bn0,bn0,bn0,bn0};
    acc[5] = (f32x4){bn1,bn1,bn1,bn1};
#pragma unroll
    for (int ks = 0; ks < 8; ++ks){
      bfrag a = *(const bfrag*)&hsh[curb][(L & 3)*288 + ks*32 + (L >> 4)*8];
      acc[0] = __builtin_amdgcn_mfma_f32_16x16x32_bf16(a, Wf[0][ks], acc[0], 0,0,0);
      acc[1] = __builtin_amdgcn_mfma_f32_16x16x32_bf16(a, Wf[1][ks], acc[1], 0,0,0);
      acc[2] = __builtin_amdgcn_mfma_f32_16x16x32_bf16(a, Wf[2][ks], acc[2], 0,0,0);
      acc[3] = __builtin_amdgcn_mfma_f32_16x16x32_bf16(a, Wf[3][ks], acc[3], 0,0,0);
      acc[4] = __builtin_amdgcn_mfma_f32_16x16x32_bf16(a, Wf[4][ks], acc[4], 0,0,0);
      acc[5] = __builtin_amdgcn_mfma_f32_16x16x32_bf16(a, Wf[5][ks], acc[5], 0,0,0);
    }
    // every q-group holds h-rows 0-3 in regs 0-3 (A rows repeat mod 4):
    // this lane consumes reg q of each acc for its (row=q, cols c0/c1).
    float gr0 = selq(acc[0], q), gr1 = selq(acc[1], q);
    float gz0 = selq(acc[2], q), gz1 = selq(acc[3], q);
    float gn0 = selq(acc[4], q), gn1 = selq(acc[5], q);
    float r0 = sigm(b2f(X0) + gr0), r1 = sigm(b2f(X1) + gr1);
    float z0 = sigm(b2f(X2) + gz0), z1 = sigm(b2f(X3) + gz1);
    float n0 = tanh_(b2f(X4) + r0*gn0), n1 = tanh_(b2f(X5) + r1*gn1);
    float h0 = n0 + z0*(hp0 - n0);              // (1-z)n + z*h
    float h1 = n1 + z1*(hp1 - n1);
    hp0 = h0; hp1 = h1;
    hsh[nxtb][q*288 + c0] = f2b(h0);
    hsh[nxtb][q*288 + c1] = f2b(h1);
    if (tcur == sl){                             // last step with t+1<=seq_len
      float* o = out + (size_t)(b0+q)*HH + c0;
      o[0] = h0; o[16] = h1;
    }
  };

  const size_t tadv = 2*(size_t)BB*G3;
  for (int tl = 0; tl < Tc; tl += 2){
    gru_step(0, 1, xE0, xE1, xE2, xE3, xE4, xE5, tl);
    // reload in place for t+2: issued at end of step t, used at t+2 (~2 steps
    // of latency budget); raw barriers never drain vmcnt.
    if (tl + 2 < Tc) bE += tadv;                 // clamp: final reload is dead
    xE0 = bE[lo];     xE1 = bE[lo+16];
    xE2 = bE[lo+256]; xE3 = bE[lo+272];
    xE4 = bE[lo+512]; xE5 = bE[lo+528];
    barrier_lgkm();
    gru_step(1, 0, xO0, xO1, xO2, xO3, xO4, xO5, tl + 1);
    if (tl + 3 < Tc) bO += tadv;
    xO0 = bO[lo];     xO1 = bO[lo+16];
    xO2 = bO[lo+256]; xO3 = bO[lo+272];
    xO4 = bO[lo+512]; xO5 = bO[lo+528];
    barrier_lgkm();
  }
  hws[(b0+q)*HH + c0] = hp0;
  hws[(b0+q)*HH + c1] = hp1;
}

// ---------------------------------------------------------------------------
// ws layout: [0, 384K) W_hh frag-bf16 | [384K, 768K) W_ih frag-bf16
//            [768K, 768K+3K) bsum fp32 | [1M, 2M) persistent h fp32
//            [3M, ...) xi chunk bf16.  Tc auto-halved until chunk fits ws.
// ---------------------------------------------------------------------------
extern "C" void kernel_launch(void* const* d_in, const int* in_sizes, int n_in,
                              void* d_out, int out_size, void* d_ws, size_t ws_size,
                              hipStream_t stream)
{
  (void)in_sizes; (void)n_in; (void)out_size;
  const float* x   = (const float*)d_in[0];
  const int*   seq = (const int*)  d_in[1];
  const float* Wih = (const float*)d_in[2];
  const float* Whh = (const float*)d_in[3];
  const float* bih = (const float*)d_in[4];
  const float* bhh = (const float*)d_in[5];
  float* out = (float*)d_out;
  char* ws = (char*)d_ws;
  unsigned short* Whhb = (unsigned short*)(ws);
  unsigned short* Wihb = (unsigned short*)(ws + 393216);
  float* bsum = (float*)(ws + 786432);
  float* hws = (float*)(ws + (1u<<20));
  unsigned short* xiw = (unsigned short*)(ws + 3u*(1u<<20));
  size_t avail = (ws_size > (size_t)(3u<<20)) ? ws_size - (size_t)(3u<<20) : 0;
  int Tc = TT;
  while (Tc > 16 && (size_t)Tc*BB*G3*2 > avail) Tc >>= 1;

  k_init<<<dim3(1024), dim3(256), 0, stream>>>(Wih, Whh, bih, bhh, Wihb, Whhb, bsum, hws, out);
  for (int t0 = 0; t0 < TT; t0 += Tc){
    k_proj<<<dim3((BB/256)*Tc), dim3(256), 0, stream>>>(x, Wihb, bsum, xiw, t0, Tc);
    k_rec <<<dim3(256), dim3(512), 0, stream>>>(xiw, Whhb, bhh, seq, hws, out, t0, Tc);
  }
}